// Round 14
// baseline (2130.324 us; speedup 1.0000x reference)
//
#include <hip/hip_runtime.h>
#include <math.h>

#define NPTS 16384
#define NBATCH 8
#define CIN 128
#define COUT 256
#define NP 1024
#define NS 32

#define NCELL 512     // 8x8x8 Morton cells
#define FPS_T 512     // 8 waves, 2/SIMD
#define NSLOT 32      // tiles per wave; tile = 64 consecutive sorted pts

// ---------------- spatial sort preprocessing ----------------
__device__ __forceinline__ int cell_of(float x, float y, float z)
{
  int ix = (int)(x * 8.0f); ix = ix < 0 ? 0 : (ix > 7 ? 7 : ix);
  int iy = (int)(y * 8.0f); iy = iy < 0 ? 0 : (iy > 7 ? 7 : iy);
  int iz = (int)(z * 8.0f); iz = iz < 0 ? 0 : (iz > 7 ? 7 : iz);
  int m = 0;
#pragma unroll
  for (int b = 0; b < 3; ++b)
    m |= (((ix >> b) & 1) << (3 * b)) | (((iy >> b) & 1) << (3 * b + 1))
       | (((iz >> b) & 1) << (3 * b + 2));
  return m;
}

__global__ void zero_hist_kernel(int* __restrict__ hist)
{
  hist[blockIdx.x * NCELL + threadIdx.x] = 0;
}

__global__ void hist_kernel(const float* __restrict__ xyz, int* __restrict__ hist)
{
  const int i = blockIdx.x * 256 + threadIdx.x;
  const int b = i >> 14, n = i & (NPTS - 1);
  const float* p = xyz + ((size_t)b * NPTS + n) * 3;
  atomicAdd(&hist[b * NCELL + cell_of(p[0], p[1], p[2])], 1);
}

__global__ void scan_kernel(const int* __restrict__ hist, int* __restrict__ cursor)
{
  __shared__ int s[NCELL];
  const int b = blockIdx.x, t = threadIdx.x;
  const int h = hist[b * NCELL + t];
  s[t] = h;
  __syncthreads();
  for (int off = 1; off < NCELL; off <<= 1) {
    const int v = (t >= off) ? s[t - off] : 0;
    __syncthreads();
    s[t] += v;
    __syncthreads();
  }
  cursor[b * NCELL + t] = s[t] - h;   // exclusive
}

__global__ void scatter_kernel(const float* __restrict__ xyz, int* __restrict__ cursor,
                               float2* __restrict__ sxy2S, float* __restrict__ szS,
                               int* __restrict__ siS)
{
  const int i = blockIdx.x * 256 + threadIdx.x;
  const int b = i >> 14, n = i & (NPTS - 1);
  const float* p = xyz + ((size_t)b * NPTS + n) * 3;
  const float x = p[0], y = p[1], z = p[2];
  const int pos = atomicAdd(&cursor[b * NCELL + cell_of(x, y, z)], 1);
  const size_t o = (size_t)b * NPTS + pos;
  sxy2S[o] = make_float2(x, y);
  szS[o] = z;
  siS[o] = n;
}

// ---------------- DPP helpers ----------------
template <int CTRL>
__device__ __forceinline__ void dpp_max64(unsigned& hi, unsigned& lo)
{
  const unsigned ohi = (unsigned)__builtin_amdgcn_update_dpp((int)hi, (int)hi, CTRL, 0xF, 0xF, false);
  const unsigned olo = (unsigned)__builtin_amdgcn_update_dpp((int)lo, (int)lo, CTRL, 0xF, 0xF, false);
  const bool t = (ohi > hi) || (ohi == hi && olo > lo);
  hi = t ? ohi : hi;
  lo = t ? olo : lo;
}
template <int CTRL>
__device__ __forceinline__ float dppmaxf(float v)
{
  const float o = __uint_as_float((unsigned)__builtin_amdgcn_update_dpp(
      (int)__float_as_uint(v), (int)__float_as_uint(v), CTRL, 0xF, 0xF, false));
  return fmaxf(v, o);
}
template <int CTRL>
__device__ __forceinline__ float dppminf(float v)
{
  const float o = __uint_as_float((unsigned)__builtin_amdgcn_update_dpp(
      (int)__float_as_uint(v), (int)__float_as_uint(v), CTRL, 0xF, 0xF, false));
  return fminf(v, o);
}
#define RED6F(v) v = dppmaxf<0x111>(v); v = dppmaxf<0x112>(v); v = dppmaxf<0x114>(v); \
                 v = dppmaxf<0x118>(v); v = dppmaxf<0x142>(v); v = dppmaxf<0x143>(v);
#define RED6FN(v) v = dppminf<0x111>(v); v = dppminf<0x112>(v); v = dppminf<0x114>(v); \
                  v = dppminf<0x118>(v); v = dppminf<0x142>(v); v = dppminf<0x143>(v);
#define RED64_6(h, l) dpp_max64<0x111>(h, l); dpp_max64<0x112>(h, l); \
                      dpp_max64<0x114>(h, l); dpp_max64<0x118>(h, l); \
                      dpp_max64<0x142>(h, l); dpp_max64<0x143>(h, l);
#define RED64_3(h, l) dpp_max64<0x111>(h, l); dpp_max64<0x112>(h, l); \
                      dpp_max64<0x114>(h, l);

// ---------------- FPS ----------------
// 1 block/batch, 512 thr (8 waves, 2/SIMD). Round-13's verified lean
// structure (register-only tile test; UPD = LDS-xy + L2-z + fused RED64_6)
// at HALF the waves: rounds 7-13 showed the fixed per-wave cost (test 22 +
// combine 35 instr) replicated across 16 waves was the issue-bound floor.
// 512-thr blocks get ~100 VGPRs (measured r12) -> dist[32]+pidp[16]+bbox 8+
// key 2 (~83) fits without spill. Tile (w,j) = 64 consecutive Morton pts at
// sp=(j<<9)+t; lane (lane&31) caches tile (lane&31)'s bbox+key in REGISTERS;
// one ballot tests all 32 tiles. Combine = 8 slots, LDS-only + speculative
// winner-z. Tie-break exact (max invpid = min original idx). 1 barrier/iter.
__global__ __launch_bounds__(FPS_T)
void fps_kernel(const float* __restrict__ xyz,
                const float2* __restrict__ sxy2S, const float* __restrict__ szS,
                const int* __restrict__ siS, int* __restrict__ fps_idx)
{
#pragma clang fp contract(off)
  __shared__ float2 XY[NPTS];                   // 128 KB, sorted order
  __shared__ unsigned long long redk[2][8];
  const int b = blockIdx.x;
  const int t = threadIdx.x;
  const int lane = t & 63, w = t >> 6;          // 8 waves
  const int l32 = lane & 31;
  const float* __restrict__ X = xyz + (size_t)b * NPTS * 3;
  const float* __restrict__ ZS = szS + (size_t)b * NPTS;
  const int* __restrict__ IS = siS + (size_t)b * NPTS;
  const float2* __restrict__ XYS = sxy2S + (size_t)b * NPTS;

  float dist[NSLOT];
  int pidp[NSLOT / 2];                          // 2x invpid (14b) per u32
  float cbxn = 0, cbxx = 0, cbyn = 0, cbyx = 0, cbzn = 0, cbzx = 0;  // tile l32 bbox
  unsigned ckh = __float_as_uint(1e10f), ckl = 0;                    // tile l32 key
  unsigned tmpinv = 0;
#pragma unroll
  for (int j = 0; j < NSLOT; ++j) {
    const int sp = (j << 9) + t;                // sorted pos owned by (j,t)
    const float2 v = XYS[sp];                   // coalesced
    XY[sp] = v;                                 // conflict-free ds_write_b64
    const float zz = ZS[sp];                    // coalesced
    const unsigned inv = (unsigned)(IS[sp] ^ 0x3FFF);
    if ((j & 1) == 0) tmpinv = inv; else pidp[j >> 1] = (int)(tmpinv | (inv << 16));
    dist[j] = 1e10f;
    // tile (w,j) bbox + initial key (uniform dist -> winner = max inv)
    float xn = v.x, xx = v.x, yn = v.y, yx = v.y, zn = zz, zx = zz;
    RED6FN(xn) RED6F(xx) RED6FN(yn) RED6F(yx) RED6FN(zn) RED6F(zx)
    unsigned kh0 = __float_as_uint(1e10f), kl0 = (inv << 14) | (unsigned)sp;
    RED64_6(kh0, kl0)
    const float sxn = __uint_as_float((unsigned)__builtin_amdgcn_readlane(__float_as_int(xn), 63));
    const float sxx = __uint_as_float((unsigned)__builtin_amdgcn_readlane(__float_as_int(xx), 63));
    const float syn = __uint_as_float((unsigned)__builtin_amdgcn_readlane(__float_as_int(yn), 63));
    const float syx = __uint_as_float((unsigned)__builtin_amdgcn_readlane(__float_as_int(yx), 63));
    const float szn = __uint_as_float((unsigned)__builtin_amdgcn_readlane(__float_as_int(zn), 63));
    const float szx = __uint_as_float((unsigned)__builtin_amdgcn_readlane(__float_as_int(zx), 63));
    const unsigned skl = (unsigned)__builtin_amdgcn_readlane((int)kl0, 63);
    if (l32 == j) {
      cbxn = sxn; cbxx = sxx; cbyn = syn; cbyx = syx; cbzn = szn; cbzx = szx;
      ckl = skl;                                // ckh already 1e10 bits
    }
  }
  __syncthreads();

  unsigned wkh = __float_as_uint(1e10f), wkl = 0;  // cached wave key
  int cur = 0;
  float lx = X[0], ly = X[1], lz = X[2];

  for (int k = 0; k < NP; ++k) {
    if (t == 0) fps_idx[b * NP + k] = cur;

    // lane tests tile (w, lane&31) — register-only exact skip
    const float ddx = fmaxf(fmaxf(cbxn - lx, lx - cbxx), 0.0f);
    const float ddy = fmaxf(fmaxf(cbyn - ly, ly - cbyx), 0.0f);
    const float ddz = fmaxf(fmaxf(cbzn - lz, lz - cbzx), 0.0f);
    const float db2 = ((ddx * ddx) + (ddy * ddy)) + (ddz * ddz);
    const bool act = db2 <= __uint_as_float(ckh) * 1.00001f;
    const unsigned msk = __builtin_amdgcn_readfirstlane(
        (unsigned)(__ballot(act) & 0xFFFFFFFFull));  // lanes 32-63 mirror 0-31

    if (msk) {
      // active tiles: update + fused exact key recompute; z from L2-hot ZS
#define UPD(J) if (msk & (1u << (J))) {                                   \
        const int sp_ = ((J) << 9) + t;                                   \
        const float2 v = XY[sp_];                                         \
        const float zz = ZS[sp_];                                         \
        const float dx = v.x - lx, dy = v.y - ly, dz = zz - lz;           \
        const float d = ((dx * dx) + (dy * dy)) + (dz * dz);              \
        const float nd = fminf(dist[(J)], d);                             \
        dist[(J)] = nd;                                                   \
        const unsigned inv = ((unsigned)pidp[(J) >> 1] >> (((J) & 1) * 16)) & 0xFFFFu; \
        unsigned kh = __float_as_uint(nd), kl = (inv << 14) | (unsigned)sp_; \
        RED64_6(kh, kl)                                                   \
        const unsigned skh = (unsigned)__builtin_amdgcn_readlane((int)kh, 63); \
        const unsigned skl = (unsigned)__builtin_amdgcn_readlane((int)kl, 63); \
        if (l32 == (J)) { ckh = skh; ckl = skl; } }
      UPD(0)  UPD(1)  UPD(2)  UPD(3)  UPD(4)  UPD(5)  UPD(6)  UPD(7)
      UPD(8)  UPD(9)  UPD(10) UPD(11) UPD(12) UPD(13) UPD(14) UPD(15)
      UPD(16) UPD(17) UPD(18) UPD(19) UPD(20) UPD(21) UPD(22) UPD(23)
      UPD(24) UPD(25) UPD(26) UPD(27) UPD(28) UPD(29) UPD(30) UPD(31)
#undef UPD
      // wave key over the 32 cached tile keys (lanes 32-63 hold mirrors)
      unsigned h = ckh, l2 = ckl;
      RED64_6(h, l2)
      wkh = (unsigned)__builtin_amdgcn_readlane((int)h, 63);
      wkl = (unsigned)__builtin_amdgcn_readlane((int)l2, 63);
    }
    const int p = k & 1;
    if (lane == 0)
      redk[p][w] = ((unsigned long long)wkh << 32) | wkl;
    __syncthreads();

    // cross-wave combine: 8 slots; speculative winner-z overlaps the DPP chain
    const unsigned long long kj = redk[p][lane & 7];
    const unsigned shi = (unsigned)(kj >> 32), slo = (unsigned)kj;
    const float sgz = ZS[(int)(slo & 0x3FFFu)]; // global (L2), overlapped
    unsigned h2 = shi, l3 = slo;
    RED64_3(h2, l3)                             // lane 7 of each 16-row = block max
    const unsigned kmh = (unsigned)__builtin_amdgcn_readlane((int)h2, 7);
    const unsigned kml = (unsigned)__builtin_amdgcn_readlane((int)l3, 7);
    cur = (int)((kml >> 14) & 0x3FFFu) ^ 0x3FFF;
    const unsigned long long tmsk = __ballot(shi == kmh && slo == kml);
    const int bwl = (int)__builtin_ctzll(tmsk);
    lz = __uint_as_float((unsigned)__builtin_amdgcn_readlane(__float_as_int(sgz), bwl));
    const float2 sxy = XY[(int)(kml & 0x3FFFu)];  // uniform LDS broadcast read
    lx = sxy.x; ly = sxy.y;
    // one barrier/iter: parity double-buffer makes overwrite-while-read impossible
  }
}

// ---------------- Ball query ----------------
__global__ __launch_bounds__(256)
void ballq_kernel(const float* __restrict__ xyz, const int* __restrict__ fps_idx,
                  int* __restrict__ ball_idx)
{
#pragma clang fp contract(off)
  const int gw = (int)((blockIdx.x * blockDim.x + threadIdx.x) >> 6);
  const int lane = threadIdx.x & 63;
  const int b = gw >> 10, s = gw & 1023;
  const float* __restrict__ X = xyz + (size_t)b * NPTS * 3;
  const int ci = fps_idx[b * NP + s];
  const float cx = X[ci * 3 + 0], cy = X[ci * 3 + 1], cz = X[ci * 3 + 2];
  const float n2 = ((cx * cx) + (cy * cy)) + (cz * cz);
  int* __restrict__ out = ball_idx + (size_t)(b * NP + s) * NS;

  int cnt = 0;
  int first = -1;
  for (int c0 = 0; c0 < NPTS && cnt < NS; c0 += 64) {
    const int p = c0 + lane;
    const float x = X[p * 3 + 0], y = X[p * 3 + 1], z = X[p * 3 + 2];
    const float x2 = ((x * x) + (y * y)) + (z * z);
    const float dt = ((cx * x) + (cy * y)) + (cz * z);
    const float d2 = (n2 + x2) - (2.0f * dt);
    const bool inball = d2 < 0.04f;
    const unsigned long long mm = __ballot(inball);
    if (inball) {
      const int pos = cnt + __popcll(mm & ((1ull << lane) - 1ull));
      if (pos < NS) out[pos] = p;
    }
    if (first < 0 && mm != 0ull) first = c0 + __builtin_ctzll(mm);
    cnt += __popcll(mm);
  }
  if (cnt < NS) {
    if (first < 0) first = 0;
    if (lane >= cnt && lane < NS) out[lane] = first;
  }
}

// ---------------- Transpose feats [B][C][N] -> [B][N][C] ----------------
__global__ __launch_bounds__(256)
void transpose_kernel(const float* __restrict__ feats, float* __restrict__ featsT)
{
  __shared__ float t[32][33];
  const int b = blockIdx.z;
  const int cb = blockIdx.y * 32;
  const int nb = blockIdx.x * 32;
  const int tx = threadIdx.x;
  const int ty = threadIdx.y;
  const float* __restrict__ F = feats + (size_t)b * CIN * NPTS;
#pragma unroll
  for (int i = 0; i < 32; i += 8)
    t[ty + i][tx] = F[(size_t)(cb + ty + i) * NPTS + nb + tx];
  __syncthreads();
  float* __restrict__ FT_ = featsT + (size_t)b * NPTS * CIN;
#pragma unroll
  for (int i = 0; i < 32; i += 8)
    FT_[(size_t)(nb + ty + i) * CIN + cb + tx] = t[tx][ty + i];
}

// ---------------- Gather + max-pool ----------------
__global__ __launch_bounds__(128)
void pool_kernel(const float* __restrict__ featsT, const int* __restrict__ ball_idx,
                 float* __restrict__ pooled)
{
  const int bs = blockIdx.x;
  const int c = threadIdx.x;
  const int b = bs >> 10;
  const int* __restrict__ idx = ball_idx + (size_t)bs * NS;
  const float* __restrict__ FT_ = featsT + (size_t)b * NPTS * CIN;
  float m = -INFINITY;
#pragma unroll 4
  for (int k = 0; k < NS; ++k) {
    const int n = idx[k];
    m = fmaxf(m, FT_[(size_t)n * CIN + c]);
  }
  pooled[(size_t)bs * CIN + c] = m;
}

// ---------------- 1x1 conv + BN + LeakyReLU ----------------
#define GO 128
#define GS 64
__global__ __launch_bounds__(256, 1)
void gemm_kernel(const float* __restrict__ pooled, const float* __restrict__ W,
                 const float* __restrict__ gamma, const float* __restrict__ beta,
                 const float* __restrict__ mean, const float* __restrict__ var,
                 float* __restrict__ out)
{
  __shared__ float Wt[128 * 132];
  __shared__ float Pl[128 * 68];
  const int b = blockIdx.z;
  const int ob = blockIdx.y * GO;
  const int sb = blockIdx.x * GS;
  const int tid = threadIdx.x;

  for (int i = tid; i < GO * 128; i += 256) {
    const int o = i >> 7, c = i & 127;
    Wt[c * 132 + o] = W[(ob + o) * 128 + c];
  }
  const float* __restrict__ P = pooled + (size_t)(b * NP + sb) * 128;
  for (int i = tid; i < GS * 128; i += 256) {
    const int s = i >> 7, c = i & 127;
    Pl[c * 68 + s] = P[s * 128 + c];
  }
  __syncthreads();

  const int to = tid & 31, ts = tid >> 5;
  const int o0 = to * 4, s0 = ts * 8;
  float acc[4][8];
#pragma unroll
  for (int o = 0; o < 4; ++o)
#pragma unroll
    for (int j = 0; j < 8; ++j) acc[o][j] = 0.0f;

  for (int c = 0; c < 128; ++c) {
    const float4 wv = *(const float4*)&Wt[c * 132 + o0];
    const float4 pa = *(const float4*)&Pl[c * 68 + s0];
    const float4 pb = *(const float4*)&Pl[c * 68 + s0 + 4];
    const float wr[4] = {wv.x, wv.y, wv.z, wv.w};
    const float pr[8] = {pa.x, pa.y, pa.z, pa.w, pb.x, pb.y, pb.z, pb.w};
#pragma unroll
    for (int o = 0; o < 4; ++o)
#pragma unroll
      for (int j = 0; j < 8; ++j)
        acc[o][j] = fmaf(wr[o], pr[j], acc[o][j]);
  }

#pragma unroll
  for (int o = 0; o < 4; ++o) {
    const int oo = ob + o0 + o;
    const float sc = gamma[oo] / sqrtf(var[oo] + 1e-5f);
    const float sh = beta[oo] - mean[oo] * sc;
    float r[8];
#pragma unroll
    for (int j = 0; j < 8; ++j) {
      const float y = fmaf(acc[o][j], sc, sh);
      r[j] = (y >= 0.0f) ? y : 0.2f * y;
    }
    float* __restrict__ O = out + (size_t)(b * COUT + oo) * NP + sb + s0;
    *(float4*)&O[0] = make_float4(r[0], r[1], r[2], r[3]);
    *(float4*)&O[4] = make_float4(r[4], r[5], r[6], r[7]);
  }
}

// ---------------- launch ----------------
extern "C" void kernel_launch(void* const* d_in, const int* in_sizes, int n_in,
                              void* d_out, int out_size, void* d_ws, size_t ws_size,
                              hipStream_t stream)
{
  (void)in_sizes; (void)n_in; (void)out_size; (void)ws_size;
  const float* xyz   = (const float*)d_in[0];
  const float* feats = (const float*)d_in[1];
  const float* W     = (const float*)d_in[2];
  const float* gamma = (const float*)d_in[3];
  const float* beta  = (const float*)d_in[4];
  const float* mean  = (const float*)d_in[5];
  const float* var   = (const float*)d_in[6];
  float* out = (float*)d_out;

  char* ws = (char*)d_ws;
  // fps_idx [32KB] @0 | ball_idx [1MB] @32768 | featsT [64MB] @1081344 |
  // pooled [4MB] @68190208. Sort scratch aliases featsT head (dead before
  // transpose runs; stream order guarantees no overlap-in-time).
  int*   fps_idx  = (int*)(ws + 0);
  int*   ball_idx = (int*)(ws + 32768);
  char*  fbase    = ws + 1081344;
  float* featsT   = (float*)fbase;
  float* pooled   = (float*)(ws + 68190208);

  float2* sxy2S  = (float2*)(fbase + 0);        // 1 MB
  float*  szS    = (float*)(fbase + 1048576);   // 512 KB
  int*    siS    = (int*)(fbase + 1572864);     // 512 KB
  int*    hist   = (int*)(fbase + 2097152);     // 16 KB
  int*    cursor = (int*)(fbase + 2113536);     // 16 KB

  zero_hist_kernel<<<NBATCH, NCELL, 0, stream>>>(hist);
  hist_kernel<<<(NBATCH * NPTS) / 256, 256, 0, stream>>>(xyz, hist);
  scan_kernel<<<NBATCH, NCELL, 0, stream>>>(hist, cursor);
  scatter_kernel<<<(NBATCH * NPTS) / 256, 256, 0, stream>>>(xyz, cursor, sxy2S, szS, siS);
  fps_kernel<<<NBATCH, FPS_T, 0, stream>>>(xyz, sxy2S, szS, siS, fps_idx);
  ballq_kernel<<<(NBATCH * NP) / 4, 256, 0, stream>>>(xyz, fps_idx, ball_idx);
  transpose_kernel<<<dim3(NPTS / 32, CIN / 32, NBATCH), dim3(32, 8), 0, stream>>>(feats, featsT);
  pool_kernel<<<NBATCH * NP, CIN, 0, stream>>>(featsT, ball_idx, pooled);
  gemm_kernel<<<dim3(NP / GS, COUT / GO, NBATCH), 256, 0, stream>>>(pooled, W, gamma, beta, mean, var, out);
}

// Round 15
// 1638.302 us; speedup vs baseline: 1.3003x; 1.3003x over previous
//
#include <hip/hip_runtime.h>
#include <math.h>

#define NPTS 16384
#define NBATCH 8
#define CIN 128
#define COUT 256
#define NP 1024
#define NS 32

#define NCELL 512     // 8x8x8 Morton cells
#define FPS_T 1024    // 16 waves, 4/EU
#define FPS_PP 16     // points per thread

// ---------------- spatial sort preprocessing ----------------
__device__ __forceinline__ int cell_of(float x, float y, float z)
{
  int ix = (int)(x * 8.0f); ix = ix < 0 ? 0 : (ix > 7 ? 7 : ix);
  int iy = (int)(y * 8.0f); iy = iy < 0 ? 0 : (iy > 7 ? 7 : iy);
  int iz = (int)(z * 8.0f); iz = iz < 0 ? 0 : (iz > 7 ? 7 : iz);
  int m = 0;
#pragma unroll
  for (int b = 0; b < 3; ++b)
    m |= (((ix >> b) & 1) << (3 * b)) | (((iy >> b) & 1) << (3 * b + 1))
       | (((iz >> b) & 1) << (3 * b + 2));
  return m;
}

__global__ void zero_hist_kernel(int* __restrict__ hist)
{
  hist[blockIdx.x * NCELL + threadIdx.x] = 0;
}

__global__ void hist_kernel(const float* __restrict__ xyz, int* __restrict__ hist)
{
  const int i = blockIdx.x * 256 + threadIdx.x;
  const int b = i >> 14, n = i & (NPTS - 1);
  const float* p = xyz + ((size_t)b * NPTS + n) * 3;
  atomicAdd(&hist[b * NCELL + cell_of(p[0], p[1], p[2])], 1);
}

__global__ void scan_kernel(const int* __restrict__ hist, int* __restrict__ cursor)
{
  __shared__ int s[NCELL];
  const int b = blockIdx.x, t = threadIdx.x;
  const int h = hist[b * NCELL + t];
  s[t] = h;
  __syncthreads();
  for (int off = 1; off < NCELL; off <<= 1) {
    const int v = (t >= off) ? s[t - off] : 0;
    __syncthreads();
    s[t] += v;
    __syncthreads();
  }
  cursor[b * NCELL + t] = s[t] - h;   // exclusive
}

// Transposed-chunk layout: sorted pos p -> slot (p%16)*1024 + p/16 so FPS
// thread t's i-th point (p=t*16+i) is at [i*1024+t] (coalesced). szS is the
// compact by-sorted-pos z array used for the winner-z gather.
__global__ void scatter_kernel(const float* __restrict__ xyz, int* __restrict__ cursor,
                               float2* __restrict__ sxy2T, float* __restrict__ szT,
                               float* __restrict__ szS, int* __restrict__ siT)
{
  const int i = blockIdx.x * 256 + threadIdx.x;
  const int b = i >> 14, n = i & (NPTS - 1);
  const float* p = xyz + ((size_t)b * NPTS + n) * 3;
  const float x = p[0], y = p[1], z = p[2];
  const int pos = atomicAdd(&cursor[b * NCELL + cell_of(x, y, z)], 1);
  const int q = (pos & (FPS_PP - 1)) * FPS_T + (pos >> 4);
  const size_t o = (size_t)b * NPTS + q;
  sxy2T[o] = make_float2(x, y);
  szT[o] = z;
  siT[o] = n;
  szS[(size_t)b * NPTS + pos] = z;
}

// ---------------- DPP helpers ----------------
template <int CTRL>
__device__ __forceinline__ void dpp_max64(unsigned& hi, unsigned& lo)
{
  const unsigned ohi = (unsigned)__builtin_amdgcn_update_dpp((int)hi, (int)hi, CTRL, 0xF, 0xF, false);
  const unsigned olo = (unsigned)__builtin_amdgcn_update_dpp((int)lo, (int)lo, CTRL, 0xF, 0xF, false);
  const bool t = (ohi > hi) || (ohi == hi && olo > lo);
  hi = t ? ohi : hi;
  lo = t ? olo : lo;
}
// row_shr:1/2/4/8 = 0x111/0x112/0x114/0x118, row_bcast15 = 0x142, row_bcast31 = 0x143

// ---------------- FPS ----------------
// 1 block/batch, 1024 thr (16 waves, 4/EU). (x,y) in 128KB LDS; z/pids in regs.
// WAVE-UNIFORM cull: per-wave bbox + cached wave key (its own max dist) ->
// s_cbranch skips update AND the 6-step DPP for far waves (exec-masked
// per-thread culling saved nothing: masked lanes still issue). Key packs
// (distbits<<32 | invpid<<14 | spos): tie-break = min original idx (exact),
// and spos lets the winner (x,y) come from LDS + z from compact szS --
// speculative 16-lane loads issued before the combine shrink the serial tail.
__global__ __launch_bounds__(FPS_T)
void fps_kernel(const float* __restrict__ xyz,
                const float2* __restrict__ sxy2T, const float* __restrict__ szT,
                const float* __restrict__ szS, const int* __restrict__ siT,
                int* __restrict__ fps_idx)
{
#pragma clang fp contract(off)
  __shared__ float2 XY[FPS_PP * FPS_T];           // 128 KB
  __shared__ unsigned long long redk[2][16];
  const int b = blockIdx.x;
  const int t = threadIdx.x;
  const int lane = t & 63, w = t >> 6;            // 16 waves
  const int t16 = t << 4;
  const float* __restrict__ X = xyz + (size_t)b * NPTS * 3;
  const float* __restrict__ ZS = szS + (size_t)b * NPTS;
  const size_t B0 = (size_t)b * NPTS;

  float z[FPS_PP], dist[FPS_PP];
  int pidp[FPS_PP / 2];
  float bxn = 1e30f, bxx = -1e30f, byn = 1e30f, byx = -1e30f, bzn = 1e30f, bzx = -1e30f;
#pragma unroll
  for (int i = 0; i < FPS_PP; ++i) {
    const float2 v = sxy2T[B0 + i * FPS_T + t];   // coalesced
    XY[i * FPS_T + t] = v;                        // conflict-free ds_write_b64
    z[i] = szT[B0 + i * FPS_T + t];               // coalesced
    dist[i] = 1e10f;
    bxn = fminf(bxn, v.x); bxx = fmaxf(bxx, v.x);
    byn = fminf(byn, v.y); byx = fmaxf(byx, v.y);
    bzn = fminf(bzn, z[i]); bzx = fmaxf(bzx, z[i]);
  }
#pragma unroll
  for (int i = 0; i < FPS_PP / 2; ++i)
    pidp[i] = siT[B0 + (2 * i) * FPS_T + t] | (siT[B0 + (2 * i + 1) * FPS_T + t] << 16);
  // wave-level bbox (uniform across the wave after butterfly)
#pragma unroll
  for (int off = 1; off < 64; off <<= 1) {
    bxn = fminf(bxn, __shfl_xor(bxn, off)); bxx = fmaxf(bxx, __shfl_xor(bxx, off));
    byn = fminf(byn, __shfl_xor(byn, off)); byx = fmaxf(byx, __shfl_xor(byx, off));
    bzn = fminf(bzn, __shfl_xor(bzn, off)); bzx = fmaxf(bzx, __shfl_xor(bzx, off));
  }
  __syncthreads();

  unsigned wkh = __float_as_uint(1e10f), wkl = 0;  // cached wave-reduced key
  int   cur = 0;
  float lx = X[0], ly = X[1], lz = X[2];

  for (int k = 0; k < NP; ++k) {
    if (t == 0) fps_idx[b * NP + k] = cur;

    // wave-uniform exact skip: d_min(center, wave bbox)^2 > mt_wave*(1+1e-5)
    // => every point's reference-order distance >= its dist => exact no-op,
    // and the cached wave key (computed from unchanged dists) stays valid.
    const float ddx = fmaxf(fmaxf(bxn - lx, lx - bxx), 0.0f);
    const float ddy = fmaxf(fmaxf(byn - ly, ly - byx), 0.0f);
    const float ddz = fmaxf(fmaxf(bzn - lz, lz - bzx), 0.0f);
    const float db2 = ddx * ddx + ddy * ddy + ddz * ddz;
    const float mtw = __uint_as_float(wkh);
    if (db2 <= mtw * 1.00001f) {                  // uniform -> s_cbranch
      float m = -1.0f;
#pragma unroll
      for (int i = 0; i < FPS_PP; ++i) {
        const float2 v = XY[i * FPS_T + t];       // ds_read_b64, conflict-free
        const float dx = v.x - lx, dy = v.y - ly, dz = z[i] - lz;
        const float d = ((dx * dx) + (dy * dy)) + (dz * dz);  // exact ref op order
        const float nd = fminf(dist[i], d);
        dist[i] = nd;
        m = fmaxf(m, nd);
      }
      unsigned sel = 0;
#pragma unroll
      for (int i = 0; i < FPS_PP; ++i) {
        const int pi = (pidp[i >> 1] >> ((i & 1) * 16)) & 0xFFFF;
        const unsigned pl = ((unsigned)(pi ^ 0x3FFF) << 14) | (unsigned)(t16 + i);
        const unsigned cand = (sel > pl) ? sel : pl;
        sel = (dist[i] == m) ? cand : sel;        // tie -> max invpid = min pid
      }
      unsigned hi = __float_as_uint(m), lo = sel;
      dpp_max64<0x111>(hi, lo);
      dpp_max64<0x112>(hi, lo);
      dpp_max64<0x114>(hi, lo);
      dpp_max64<0x118>(hi, lo);
      dpp_max64<0x142>(hi, lo);
      dpp_max64<0x143>(hi, lo);                   // lane 63 = wave max
      wkh = (unsigned)__builtin_amdgcn_readlane((int)hi, 63);
      wkl = (unsigned)__builtin_amdgcn_readlane((int)lo, 63);
    }
    const int p = k & 1;
    if (lane == 63)
      redk[p][w] = ((unsigned long long)wkh << 32) | wkl;
    __syncthreads();

    // cross-wave combine (all waves redundantly); speculative winner loads
    // (z from szS, xy from LDS) issued BEFORE the DPP combine to hide latency
    const unsigned long long kj = redk[p][lane & 15];
    const unsigned shi = (unsigned)(kj >> 32), slo = (unsigned)kj;
    const int sposj = (int)(slo & 0x3FFFu);
    const float sgz = ZS[sposj];                  // global, L2 (~200cy, overlapped)
    const float2 sxy = XY[(sposj & 15) * FPS_T + (sposj >> 4)];  // LDS (~50cy)
    unsigned h2 = shi, l2 = slo;
    dpp_max64<0x111>(h2, l2);
    dpp_max64<0x112>(h2, l2);
    dpp_max64<0x114>(h2, l2);
    dpp_max64<0x118>(h2, l2);                     // lane 15 of each row = global max
    const unsigned kmh = (unsigned)__builtin_amdgcn_readlane((int)h2, 15);
    const unsigned kml = (unsigned)__builtin_amdgcn_readlane((int)l2, 15);
    cur = (int)((kml >> 14) & 0x3FFFu) ^ 0x3FFF;  // winner original pid
    const unsigned long long tmsk = __ballot(shi == kmh && slo == kml) & 0xFFFFull;
    const int bwl = (int)__builtin_ctzll(tmsk);
    lx = __uint_as_float((unsigned)__builtin_amdgcn_readlane(__float_as_int(sxy.x), bwl));
    ly = __uint_as_float((unsigned)__builtin_amdgcn_readlane(__float_as_int(sxy.y), bwl));
    lz = __uint_as_float((unsigned)__builtin_amdgcn_readlane(__float_as_int(sgz), bwl));
    // one barrier/iter: parity double-buffer makes overwrite-while-read impossible
  }
}

// ---------------- Ball query ----------------
__global__ __launch_bounds__(256)
void ballq_kernel(const float* __restrict__ xyz, const int* __restrict__ fps_idx,
                  int* __restrict__ ball_idx)
{
#pragma clang fp contract(off)
  const int gw = (int)((blockIdx.x * blockDim.x + threadIdx.x) >> 6);
  const int lane = threadIdx.x & 63;
  const int b = gw >> 10, s = gw & 1023;
  const float* __restrict__ X = xyz + (size_t)b * NPTS * 3;
  const int ci = fps_idx[b * NP + s];
  const float cx = X[ci * 3 + 0], cy = X[ci * 3 + 1], cz = X[ci * 3 + 2];
  const float n2 = ((cx * cx) + (cy * cy)) + (cz * cz);
  int* __restrict__ out = ball_idx + (size_t)(b * NP + s) * NS;

  int cnt = 0;
  int first = -1;
  for (int c0 = 0; c0 < NPTS && cnt < NS; c0 += 64) {
    const int p = c0 + lane;
    const float x = X[p * 3 + 0], y = X[p * 3 + 1], z = X[p * 3 + 2];
    const float x2 = ((x * x) + (y * y)) + (z * z);
    const float dt = ((cx * x) + (cy * y)) + (cz * z);
    const float d2 = (n2 + x2) - (2.0f * dt);
    const bool inball = d2 < 0.04f;
    const unsigned long long mm = __ballot(inball);
    if (inball) {
      const int pos = cnt + __popcll(mm & ((1ull << lane) - 1ull));
      if (pos < NS) out[pos] = p;
    }
    if (first < 0 && mm != 0ull) first = c0 + __builtin_ctzll(mm);
    cnt += __popcll(mm);
  }
  if (cnt < NS) {
    if (first < 0) first = 0;
    if (lane >= cnt && lane < NS) out[lane] = first;
  }
}

// ---------------- Transpose feats [B][C][N] -> [B][N][C] ----------------
__global__ __launch_bounds__(256)
void transpose_kernel(const float* __restrict__ feats, float* __restrict__ featsT)
{
  __shared__ float t[32][33];
  const int b = blockIdx.z;
  const int cb = blockIdx.y * 32;
  const int nb = blockIdx.x * 32;
  const int tx = threadIdx.x;
  const int ty = threadIdx.y;
  const float* __restrict__ F = feats + (size_t)b * CIN * NPTS;
#pragma unroll
  for (int i = 0; i < 32; i += 8)
    t[ty + i][tx] = F[(size_t)(cb + ty + i) * NPTS + nb + tx];
  __syncthreads();
  float* __restrict__ FT_ = featsT + (size_t)b * NPTS * CIN;
#pragma unroll
  for (int i = 0; i < 32; i += 8)
    FT_[(size_t)(nb + ty + i) * CIN + cb + tx] = t[tx][ty + i];
}

// ---------------- Gather + max-pool ----------------
__global__ __launch_bounds__(128)
void pool_kernel(const float* __restrict__ featsT, const int* __restrict__ ball_idx,
                 float* __restrict__ pooled)
{
  const int bs = blockIdx.x;
  const int c = threadIdx.x;
  const int b = bs >> 10;
  const int* __restrict__ idx = ball_idx + (size_t)bs * NS;
  const float* __restrict__ FT_ = featsT + (size_t)b * NPTS * CIN;
  float m = -INFINITY;
#pragma unroll 4
  for (int k = 0; k < NS; ++k) {
    const int n = idx[k];
    m = fmaxf(m, FT_[(size_t)n * CIN + c]);
  }
  pooled[(size_t)bs * CIN + c] = m;
}

// ---------------- 1x1 conv + BN + LeakyReLU ----------------
#define GO 128
#define GS 64
__global__ __launch_bounds__(256, 1)
void gemm_kernel(const float* __restrict__ pooled, const float* __restrict__ W,
                 const float* __restrict__ gamma, const float* __restrict__ beta,
                 const float* __restrict__ mean, const float* __restrict__ var,
                 float* __restrict__ out)
{
  __shared__ float Wt[128 * 132];
  __shared__ float Pl[128 * 68];
  const int b = blockIdx.z;
  const int ob = blockIdx.y * GO;
  const int sb = blockIdx.x * GS;
  const int tid = threadIdx.x;

  for (int i = tid; i < GO * 128; i += 256) {
    const int o = i >> 7, c = i & 127;
    Wt[c * 132 + o] = W[(ob + o) * 128 + c];
  }
  const float* __restrict__ P = pooled + (size_t)(b * NP + sb) * 128;
  for (int i = tid; i < GS * 128; i += 256) {
    const int s = i >> 7, c = i & 127;
    Pl[c * 68 + s] = P[s * 128 + c];
  }
  __syncthreads();

  const int to = tid & 31, ts = tid >> 5;
  const int o0 = to * 4, s0 = ts * 8;
  float acc[4][8];
#pragma unroll
  for (int o = 0; o < 4; ++o)
#pragma unroll
    for (int j = 0; j < 8; ++j) acc[o][j] = 0.0f;

  for (int c = 0; c < 128; ++c) {
    const float4 wv = *(const float4*)&Wt[c * 132 + o0];
    const float4 pa = *(const float4*)&Pl[c * 68 + s0];
    const float4 pb = *(const float4*)&Pl[c * 68 + s0 + 4];
    const float wr[4] = {wv.x, wv.y, wv.z, wv.w};
    const float pr[8] = {pa.x, pa.y, pa.z, pa.w, pb.x, pb.y, pb.z, pb.w};
#pragma unroll
    for (int o = 0; o < 4; ++o)
#pragma unroll
      for (int j = 0; j < 8; ++j)
        acc[o][j] = fmaf(wr[o], pr[j], acc[o][j]);
  }

#pragma unroll
  for (int o = 0; o < 4; ++o) {
    const int oo = ob + o0 + o;
    const float sc = gamma[oo] / sqrtf(var[oo] + 1e-5f);
    const float sh = beta[oo] - mean[oo] * sc;
    float r[8];
#pragma unroll
    for (int j = 0; j < 8; ++j) {
      const float y = fmaf(acc[o][j], sc, sh);
      r[j] = (y >= 0.0f) ? y : 0.2f * y;
    }
    float* __restrict__ O = out + (size_t)(b * COUT + oo) * NP + sb + s0;
    *(float4*)&O[0] = make_float4(r[0], r[1], r[2], r[3]);
    *(float4*)&O[4] = make_float4(r[4], r[5], r[6], r[7]);
  }
}

// ---------------- launch ----------------
extern "C" void kernel_launch(void* const* d_in, const int* in_sizes, int n_in,
                              void* d_out, int out_size, void* d_ws, size_t ws_size,
                              hipStream_t stream)
{
  (void)in_sizes; (void)n_in; (void)out_size; (void)ws_size;
  const float* xyz   = (const float*)d_in[0];
  const float* feats = (const float*)d_in[1];
  const float* W     = (const float*)d_in[2];
  const float* gamma = (const float*)d_in[3];
  const float* beta  = (const float*)d_in[4];
  const float* mean  = (const float*)d_in[5];
  const float* var   = (const float*)d_in[6];
  float* out = (float*)d_out;

  char* ws = (char*)d_ws;
  // fps_idx [32KB] @0 | ball_idx [1MB] @32768 | featsT [64MB] @1081344 |
  // pooled [4MB] @68190208. Sort scratch aliases featsT head (dead before
  // transpose runs; stream order guarantees no overlap-in-time).
  int*   fps_idx  = (int*)(ws + 0);
  int*   ball_idx = (int*)(ws + 32768);
  char*  fbase    = ws + 1081344;
  float* featsT   = (float*)fbase;
  float* pooled   = (float*)(ws + 68190208);

  float2* sxy2T  = (float2*)(fbase + 0);        // 1 MB
  float*  szT    = (float*)(fbase + 1048576);   // 512 KB
  int*    siT    = (int*)(fbase + 1572864);     // 512 KB
  float*  szS    = (float*)(fbase + 2097152);   // 512 KB
  int*    hist   = (int*)(fbase + 2621440);     // 16 KB
  int*    cursor = (int*)(fbase + 2637824);     // 16 KB

  zero_hist_kernel<<<NBATCH, NCELL, 0, stream>>>(hist);
  hist_kernel<<<(NBATCH * NPTS) / 256, 256, 0, stream>>>(xyz, hist);
  scan_kernel<<<NBATCH, NCELL, 0, stream>>>(hist, cursor);
  scatter_kernel<<<(NBATCH * NPTS) / 256, 256, 0, stream>>>(xyz, cursor, sxy2T, szT, szS, siT);
  fps_kernel<<<NBATCH, FPS_T, 0, stream>>>(xyz, sxy2T, szT, szS, siT, fps_idx);
  ballq_kernel<<<(NBATCH * NP) / 4, 256, 0, stream>>>(xyz, fps_idx, ball_idx);
  transpose_kernel<<<dim3(NPTS / 32, CIN / 32, NBATCH), dim3(32, 8), 0, stream>>>(feats, featsT);
  pool_kernel<<<NBATCH * NP, CIN, 0, stream>>>(featsT, ball_idx, pooled);
  gemm_kernel<<<dim3(NP / GS, COUT / GO, NBATCH), 256, 0, stream>>>(pooled, W, gamma, beta, mean, var, out);
}